// Round 8
// baseline (165.063 us; speedup 1.0000x reference)
//
#include <hip/hip_runtime.h>
#include <hip/hip_cooperative_groups.h>
#include <math.h>

namespace cg = cooperative_groups;

#define NB 64
#define NN 1024
#define NC 128
#define NK 512
#define NBLK 256
#define NTHR 1024

// Single cooperative kernel: score -> rank -> xpool+scan -> write,
// separated by grid.sync() instead of kernel boundaries.
__global__ __launch_bounds__(NTHR, 1) void fused_kernel(
    const float* __restrict__ x, const float* __restrict__ adj,
    const float* __restrict__ w, double* __restrict__ sacc,
    unsigned* __restrict__ bm, int* __restrict__ perm,
    float* __restrict__ gate, int* __restrict__ inv,
    float* __restrict__ x_pool, float* __restrict__ adj_pooled)
{
    cg::grid_group grid = cg::this_grid();
    __shared__ __align__(16) unsigned char shraw[13 * 1024];

    const int t = threadIdx.x;
    const int gtid = blockIdx.x * NTHR + t;        // 0..262143

    // ---------- P1: score — fp64 dot, 16 lanes/row, 4 virtual passes ----------
    #pragma unroll
    for (int it = 0; it < 4; ++it) {
        int v = it * (NBLK * NTHR) + gtid;         // 0..1048575
        int row = v >> 4;                          // 0..65535
        int c0 = (v & 15) * 8;
        float4 a  = *(const float4*)(x + (size_t)row * NC + c0);
        float4 bb = *(const float4*)(x + (size_t)row * NC + c0 + 4);
        float4 wa = *(const float4*)(w + c0);
        float4 wb = *(const float4*)(w + c0 + 4);
        double acc = (double)a.x * wa.x + (double)a.y * wa.y
                   + (double)a.z * wa.z + (double)a.w * wa.w
                   + (double)bb.x * wb.x + (double)bb.y * wb.y
                   + (double)bb.z * wb.z + (double)bb.w * wb.w;
        acc += __shfl_xor(acc, 1, 64);
        acc += __shfl_xor(acc, 2, 64);
        acc += __shfl_xor(acc, 4, 64);
        acc += __shfl_xor(acc, 8, 64);
        if ((v & 15) == 0) sacc[row] = acc;
    }
    grid.sync();

    // ---------- P2: rank — block (b,q); j-loop split 4-way across block ----------
    {
        double* s   = (double*)shraw;                      // [1024] 8 KB
        int*    rp  = (int*)(shraw + 8192);                // [1024] 4 KB
        double* prnw = (double*)(shraw + 8192 + 4096);     // 1 double
        const int b = blockIdx.x >> 2;
        const int q = blockIdx.x & 3;
        for (int idx = t; idx < NN; idx += NTHR)
            s[idx] = sacc[(size_t)b * NN + idx];
        if (t < 64) {
            double p = (double)w[t] * (double)w[t]
                     + (double)w[t + 64] * (double)w[t + 64];
            #pragma unroll
            for (int off = 32; off > 0; off >>= 1)
                p += __shfl_xor(p, off, 64);
            if (t == 0) *prnw = 1.0 / sqrt(p);
        }
        __syncthreads();

        const int n  = q * 256 + (t & 255);
        const int jc = t >> 8;                     // 0..3
        const double my = s[n];
        int r = 0;
        #pragma unroll 8
        for (int j = jc * 256; j < jc * 256 + 256; ++j) {
            double o = s[j];
            r += (o > my) || ((o == my) && (j < n));
        }
        rp[t] = r;
        __syncthreads();
        if (jc == 0) {
            int rr = rp[t] + rp[t + 256] + rp[t + 512] + rp[t + 768];
            inv[b * NN + n] = (rr < NK) ? rr : -1;
            if (rr < NK) {
                perm[b * NK + rr] = n;
                gate[b * NK + rr] = (float)tanh(my * (*prnw));
            }
        }
    }
    grid.sync();

    // ---------- P3a: xpool — 4 float4 per thread ----------
    #pragma unroll
    for (int i2 = 0; i2 < 4; ++i2) {
        int id = i2 * (NBLK * NTHR) + gtid;        // < NB*NK*NC/4
        int c4 = id & (NC / 4 - 1);
        int bi = id >> 5;
        int b2 = bi >> 9;
        int pi = perm[bi];
        float g = gate[bi];
        float4 vv = *(const float4*)(x + ((size_t)b2 * NN + pi) * NC + c4 * 4);
        vv.x *= g; vv.y *= g; vv.z *= g; vv.w *= g;
        *(float4*)(x_pool + (size_t)id * 4) = vv;
    }

    // ---------- P3b: scan — forward bits, 2-deep prefetch (R7 scheme) ----------
    {
        unsigned* bits = (unsigned*)shraw;                 // [128*17] 8.5 KB
        int* sinv      = (int*)(shraw + 8704);             // [1024] 4 KB
        const int b = blockIdx.x >> 2;
        const int chunk = blockIdx.x & 3;
        for (int idx = t; idx < 128 * 17; idx += NTHR) bits[idx] = 0;
        for (int idx = t; idx < NN; idx += NTHR) sinv[idx] = inv[b * NN + idx];
        __syncthreads();

        const float* ab = adj + (size_t)b * NN * NN;
        const int* permb = perm + b * NK + chunk * 128;
        const int g  = t >> 8;
        const int lt = t & 255;

        int il = g;
        float4 v0 = *(const float4*)(ab + (size_t)permb[il] * NN + lt * 4);
        float4 v1 = *(const float4*)(ab + (size_t)permb[il + 4] * NN + lt * 4);
        for (int it = 0; it < 32; ++it) {
            float4 vn = v0;
            if (it < 30)
                vn = *(const float4*)(ab + (size_t)permb[il + 8] * NN + lt * 4);
            #pragma unroll
            for (int u = 0; u < 4; ++u) {
                if (((const float*)&v0)[u] != 0.0f) {
                    int j = sinv[lt * 4 + u];
                    if (j >= 0)
                        atomicOr(&bits[il * 17 + (j >> 5)], 1u << (j & 31));
                }
            }
            v0 = v1; v1 = vn; il += 4;
        }
        __syncthreads();
        for (int idx = t; idx < 2048; idx += NTHR) {
            int dil = idx & 127, wd = idx >> 7;
            bm[(size_t)b * 8192 + wd * 512 + chunk * 128 + dil] = bits[dil * 17 + wd];
        }
    }
    grid.sync();

    // ---------- P4: write — 2 slabs per block (R7 scheme) ----------
    {
        unsigned* tcb = (unsigned*)shraw;                  // [1024] 4 KB
        unsigned* fws = (unsigned*)(shraw + 4096);         // [64*17] 4.25 KB
        #pragma unroll
        for (int s2 = 0; s2 < 2; ++s2) {
            int sl = blockIdx.x * 2 + s2;                  // 0..511
            int b3 = sl >> 3, slab = sl & 7;
            const unsigned* bmb = bm + (size_t)b3 * 8192;
            __syncthreads();                               // LDS reuse guard
            tcb[t] = bmb[(slab * 2 + (t >> 9)) * 512 + (t & 511)];
            fws[(t & 63) * 17 + (t >> 6)] = bmb[(t >> 6) * 512 + slab * 64 + (t & 63)];
            __syncthreads();

            float* ob = adj_pooled + ((size_t)b3 * NK + slab * 64) * NK;
            #pragma unroll
            for (int it = 0; it < 8; ++it) {
                int lid = it * NTHR + t;                   // < 8192
                int i_loc = lid >> 7;
                int i = slab * 64 + i_loc;
                int j4 = (lid & 127) * 4;
                unsigned fw = fws[i_loc * 17 + (j4 >> 5)];
                uint4 tq = *(const uint4*)&tcb[(i_loc >> 5) * 512 + j4];
                float4 res;
                float* rpn = (float*)&res;
                const unsigned* tp = (const unsigned*)&tq;
                #pragma unroll
                for (int e = 0; e < 4; ++e) {
                    unsigned bit = ((fw >> ((j4 + e) & 31)) | (tp[e] >> (i & 31))) & 1u;
                    float f = (float)bit;
                    if (i == j4 + e) f += 1.0f;
                    rpn[e] = f;
                }
                *(float4*)(ob + (size_t)i_loc * NK + j4) = res;
            }
        }
    }
}

extern "C" void kernel_launch(void* const* d_in, const int* in_sizes, int n_in,
                              void* d_out, int out_size, void* d_ws, size_t ws_size,
                              hipStream_t stream) {
    const float* x   = (const float*)d_in[0];
    const float* adj = (const float*)d_in[1];
    const float* w   = (const float*)d_in[2];
    float* out = (float*)d_out;

    char* p = (char*)d_ws;
    double*   sacc = (double*)p;    p += sizeof(double) * NB * NN;        // 512 KB
    unsigned* bm   = (unsigned*)p;  p += sizeof(unsigned) * NB * 16 * NK; // 2 MB
    int*      perm = (int*)p;       p += sizeof(int) * NB * NK;           // 128 KB
    float*    gate = (float*)p;     p += sizeof(float) * NB * NK;         // 128 KB
    int*      inv  = (int*)p;                                             // 256 KB

    float* x_pool     = out;                           // NB*NK*NC
    float* adj_pooled = out + (size_t)NB * NK * NC;    // NB*NK*NK

    void* args[] = { (void*)&x, (void*)&adj, (void*)&w, (void*)&sacc,
                     (void*)&bm, (void*)&perm, (void*)&gate, (void*)&inv,
                     (void*)&x_pool, (void*)&adj_pooled };
    hipLaunchCooperativeKernel((void*)fused_kernel, dim3(NBLK), dim3(NTHR),
                               args, 0, stream);
}

// Round 9
// 80.712 us; speedup vs baseline: 2.0451x; 2.0451x over previous
//
#include <hip/hip_runtime.h>
#include <math.h>

#define NB 64
#define NN 1024
#define NC 128
#define NK 512

// K1: fused score+rank. 4 blocks/graph x 1024 threads. Each block redundantly
// computes ALL 1024 fp64 scores of its graph into LDS (x is L3-resident, so
// the 4x re-read is cheap), then ranks its 256 nodes with a 4-way j-split.
// Total order (score desc, idx asc) == jax.lax.top_k; rank on pre-tanh dot
// (monotone => same order as reference).
__global__ __launch_bounds__(1024) void scorerank_kernel(
    const float* __restrict__ x, const float* __restrict__ w,
    int* __restrict__ perm, float* __restrict__ gate, int* __restrict__ inv)
{
    __shared__ __align__(16) double s[NN];   // 8 KB
    __shared__ int rp[1024];                 // 4 KB
    __shared__ double s_rnw;
    const int b = blockIdx.x >> 2;
    const int q = blockIdx.x & 3;
    const int t = threadIdx.x;

    // ---- score: 16 lanes/row (8 cols each), 64 rows/pass, 16 passes ----
    const int c0 = (t & 15) * 8;
    const float4 wa = *(const float4*)(w + c0);
    const float4 wb = *(const float4*)(w + c0 + 4);
    #pragma unroll 4
    for (int pass = 0; pass < 16; ++pass) {
        int row = pass * 64 + (t >> 4);
        const float* xr = x + ((size_t)b * NN + row) * NC + c0;
        float4 a  = *(const float4*)xr;
        float4 bb = *(const float4*)(xr + 4);
        double acc = (double)a.x * wa.x + (double)a.y * wa.y
                   + (double)a.z * wa.z + (double)a.w * wa.w
                   + (double)bb.x * wb.x + (double)bb.y * wb.y
                   + (double)bb.z * wb.z + (double)bb.w * wb.w;
        acc += __shfl_xor(acc, 1, 64);
        acc += __shfl_xor(acc, 2, 64);
        acc += __shfl_xor(acc, 4, 64);
        acc += __shfl_xor(acc, 8, 64);
        if ((t & 15) == 0) s[row] = acc;
    }
    if (t < 64) {    // ||w||^2 via wave shuffle
        double p = (double)w[t] * (double)w[t]
                 + (double)w[t + 64] * (double)w[t + 64];
        #pragma unroll
        for (int off = 32; off > 0; off >>= 1)
            p += __shfl_xor(p, off, 64);
        if (t == 0) s_rnw = 1.0 / sqrt(p);
    }
    __syncthreads();

    // ---- rank: node n = q*256+(t&255); j-chunk jc = t>>8 (4-way split) ----
    const int n  = q * 256 + (t & 255);
    const int jc = t >> 8;
    const double my = s[n];
    int r = 0;
    #pragma unroll 8
    for (int j = jc * 256; j < jc * 256 + 256; j += 2) {
        double2 o = *(const double2*)&s[j];       // wave-uniform broadcast
        r += (o.x > my) || ((o.x == my) && (j < n));
        r += (o.y > my) || ((o.y == my) && (j + 1 < n));
    }
    rp[t] = r;
    __syncthreads();
    if (jc == 0) {
        int rr = rp[t] + rp[t + 256] + rp[t + 512] + rp[t + 768];
        inv[b * NN + n] = (rr < NK) ? rr : -1;
        if (rr < NK) {
            perm[b * NK + rr] = n;
            gate[b * NK + rr] = (float)tanh(my * s_rnw);
        }
    }
}

// K2: fused scan (blocks 0..255) + xpool (blocks 256..1279), 1024 threads.
// Scan: 4 blocks/graph, 128 pooled rows each, 2-deep row prefetch; forward
// bits only into LDS [128][17]; dump COL-MAJOR to bm[b][w][j].
__global__ __launch_bounds__(1024) void scan_xpool_kernel(
    const float* __restrict__ adj, const int* __restrict__ perm,
    const int* __restrict__ inv, const float* __restrict__ gate,
    const float* __restrict__ x, unsigned* __restrict__ bm,
    float* __restrict__ x_pool)
{
    __shared__ unsigned bits[128 * 17];   // 8.5 KB
    __shared__ int sinv[NN];              // 4 KB
    if (blockIdx.x >= 256) {
        // ---- xpool role: x_pool[bi][c] = x[b][perm[bi]][c] * gate[bi]
        int id = (blockIdx.x - 256) * 1024 + threadIdx.x;  // < NB*NK*NC/4
        int c4 = id & (NC / 4 - 1);
        int bi = id >> 5;
        int b  = bi >> 9;
        int pi = perm[bi];
        float g = gate[bi];
        float4 v = *(const float4*)(x + ((size_t)b * NN + pi) * NC + c4 * 4);
        v.x *= g; v.y *= g; v.z *= g; v.w *= g;
        *(float4*)(x_pool + (size_t)id * 4) = v;
        return;
    }
    const int b = blockIdx.x >> 2;
    const int chunk = blockIdx.x & 3;
    const int t = threadIdx.x;
    for (int idx = t; idx < 128 * 17; idx += 1024) bits[idx] = 0;
    for (int idx = t; idx < NN; idx += 1024) sinv[idx] = inv[b * NN + idx];
    __syncthreads();

    const float* ab = adj + (size_t)b * NN * NN;
    const int* permb = perm + b * NK + chunk * 128;
    const int g  = t >> 8;               // local row-group 0..3
    const int lt = t & 255;

    int il = g;                          // rows g, g+4, ..., g+124
    float4 v0 = *(const float4*)(ab + (size_t)permb[il] * NN + lt * 4);
    float4 v1 = *(const float4*)(ab + (size_t)permb[il + 4] * NN + lt * 4);
    for (int it = 0; it < 32; ++it) {
        float4 vn = v0;
        if (it < 30)                     // 2-deep prefetch
            vn = *(const float4*)(ab + (size_t)permb[il + 8] * NN + lt * 4);
        #pragma unroll
        for (int u = 0; u < 4; ++u) {
            if (((const float*)&v0)[u] != 0.0f) {
                int j = sinv[lt * 4 + u];
                if (j >= 0)
                    atomicOr(&bits[il * 17 + (j >> 5)], 1u << (j & 31));
            }
        }
        v0 = v1; v1 = vn; il += 4;
    }
    __syncthreads();
    // dump: bm[b*8192 + w*512 + chunk*128 + dil] = bits[dil*17 + w]
    for (int idx = t; idx < 2048; idx += 1024) {
        int dil = idx & 127, w = idx >> 7;
        bm[(size_t)b * 8192 + w * 512 + chunk * 128 + dil] = bits[dil * 17 + w];
    }
}

// K3: adj_pooled[b,i,j] = (fw(i,j) | trans(j,i)) + (i==j).
// 8 blocks/graph x 64 output rows, 1024 threads. Stage ONLY the slab's
// needs: 2 trans word-cols (4 KB) + 64 fw rows into padded slab (4.25 KB).
__global__ __launch_bounds__(1024) void adj_write_kernel(
    const unsigned* __restrict__ bm, float* __restrict__ out)
{
    __shared__ unsigned tcb[2 * 512];       // trans word-cols slab*2, slab*2+1
    __shared__ unsigned fws[64 * 17];       // fw slab, padded
    const int b = blockIdx.x >> 3;
    const int slab = blockIdx.x & 7;        // rows slab*64 .. +63
    const int t = threadIdx.x;
    const unsigned* bmb = bm + (size_t)b * 8192;
    {   // trans: tcb[e*512 + j] = bmb[(slab*2+e)*512 + j]
        int e = t >> 9, j = t & 511;
        tcb[t] = bmb[(slab * 2 + e) * 512 + j];
    }
    {   // fw: fws[il*17+wi] = bmb[wi*512 + slab*64 + il]
        int il = t & 63, wi = t >> 6;
        fws[il * 17 + wi] = bmb[wi * 512 + slab * 64 + il];
    }
    __syncthreads();

    float* ob = out + ((size_t)b * NK + slab * 64) * NK;
    #pragma unroll
    for (int it = 0; it < 8; ++it) {
        int lid = it * 1024 + t;            // < 8192
        int i_loc = lid >> 7;               // 0..63
        int i = slab * 64 + i_loc;
        int j4 = (lid & 127) * 4;
        unsigned fw = fws[i_loc * 17 + (j4 >> 5)];
        uint4 tq = *(const uint4*)&tcb[(i_loc >> 5) * 512 + j4];
        float4 res;
        float* rpn = (float*)&res;
        const unsigned* tp = (const unsigned*)&tq;
        #pragma unroll
        for (int e = 0; e < 4; ++e) {
            unsigned bit = ((fw >> ((j4 + e) & 31)) | (tp[e] >> (i & 31))) & 1u;
            float f = (float)bit;
            if (i == j4 + e) f += 1.0f;
            rpn[e] = f;
        }
        *(float4*)(ob + (size_t)i_loc * NK + j4) = res;
    }
}

extern "C" void kernel_launch(void* const* d_in, const int* in_sizes, int n_in,
                              void* d_out, int out_size, void* d_ws, size_t ws_size,
                              hipStream_t stream) {
    const float* x   = (const float*)d_in[0];
    const float* adj = (const float*)d_in[1];
    const float* w   = (const float*)d_in[2];
    float* out = (float*)d_out;

    char* p = (char*)d_ws;
    unsigned* bm   = (unsigned*)p;  p += sizeof(unsigned) * NB * 16 * NK; // 2 MB
    int*      perm = (int*)p;       p += sizeof(int) * NB * NK;           // 128 KB
    float*    gate = (float*)p;     p += sizeof(float) * NB * NK;         // 128 KB
    int*      inv  = (int*)p;                                             // 256 KB

    float* x_pool     = out;                           // NB*NK*NC
    float* adj_pooled = out + (size_t)NB * NK * NC;    // NB*NK*NK

    scorerank_kernel<<<NB * 4, 1024, 0, stream>>>(x, w, perm, gate, inv);
    scan_xpool_kernel<<<256 + NB * NK * NC / 4 / 1024, 1024, 0, stream>>>(
        adj, perm, inv, gate, x, bm, x_pool);
    adj_write_kernel<<<NB * 8, 1024, 0, stream>>>(bm, adj_pooled);
}

// Round 10
// 65.775 us; speedup vs baseline: 2.5095x; 1.2271x over previous
//
#include <hip/hip_runtime.h>
#include <math.h>

#define NB 64
#define NN 1024
#define NC 128
#define NK 512

// K1: fused score+rank. 4 blocks/graph x 1024 threads, XCD-swizzled so the
// 4 blocks of a graph land on the SAME XCD (round-robin i%8 heuristic) and
// share the graph's 512 KB x-panel in that XCD's L2.
__global__ __launch_bounds__(1024) void scorerank_kernel(
    const float* __restrict__ x, const float* __restrict__ w,
    int* __restrict__ perm, float* __restrict__ gate, int* __restrict__ inv)
{
    __shared__ __align__(16) double s[NN];   // 8 KB
    __shared__ int rp[1024];                 // 4 KB
    __shared__ double s_rnw;
    const int i = blockIdx.x;
    const int b = (i & 7) + ((i >> 5) << 3); // graph
    const int q = (i >> 3) & 3;              // quarter
    const int t = threadIdx.x;

    // ---- score: 16 lanes/row (8 cols each), 64 rows/pass, 16 passes ----
    const int c0 = (t & 15) * 8;
    const float4 wa = *(const float4*)(w + c0);
    const float4 wb = *(const float4*)(w + c0 + 4);
    #pragma unroll 4
    for (int pass = 0; pass < 16; ++pass) {
        int row = pass * 64 + (t >> 4);
        const float* xr = x + ((size_t)b * NN + row) * NC + c0;
        float4 a  = *(const float4*)xr;
        float4 bb = *(const float4*)(xr + 4);
        double acc = (double)a.x * wa.x + (double)a.y * wa.y
                   + (double)a.z * wa.z + (double)a.w * wa.w
                   + (double)bb.x * wb.x + (double)bb.y * wb.y
                   + (double)bb.z * wb.z + (double)bb.w * wb.w;
        acc += __shfl_xor(acc, 1, 64);
        acc += __shfl_xor(acc, 2, 64);
        acc += __shfl_xor(acc, 4, 64);
        acc += __shfl_xor(acc, 8, 64);
        if ((t & 15) == 0) s[row] = acc;
    }
    if (t < 64) {    // ||w||^2 via wave shuffle
        double p = (double)w[t] * (double)w[t]
                 + (double)w[t + 64] * (double)w[t + 64];
        #pragma unroll
        for (int off = 32; off > 0; off >>= 1)
            p += __shfl_xor(p, off, 64);
        if (t == 0) s_rnw = 1.0 / sqrt(p);
    }
    __syncthreads();

    // ---- rank: node n = q*256+(t&255); j-chunk jc = t>>8 (4-way split) ----
    const int n  = q * 256 + (t & 255);
    const int jc = t >> 8;
    const double my = s[n];
    int r = 0;
    #pragma unroll 8
    for (int j = jc * 256; j < jc * 256 + 256; j += 2) {
        double2 o = *(const double2*)&s[j];       // wave-uniform broadcast
        r += (o.x > my) || ((o.x == my) && (j < n));
        r += (o.y > my) || ((o.y == my) && (j + 1 < n));
    }
    rp[t] = r;
    __syncthreads();
    if (jc == 0) {
        int rr = rp[t] + rp[t + 256] + rp[t + 512] + rp[t + 768];
        inv[b * NN + n] = (rr < NK) ? rr : -1;
        if (rr < NK) {
            perm[b * NK + rr] = n;
            gate[b * NK + rr] = (float)tanh(my * s_rnw);
        }
    }
}

// K2: fused scan (blocks 0..511) + xpool (blocks 512..1535), 1024 threads.
// Scan: 8 blocks/graph, 64 pooled rows each, 3-deep row prefetch; forward
// bits only into LDS [64][17]; dump COL-MAJOR to bm[b][w][j].
__global__ __launch_bounds__(1024) void scan_xpool_kernel(
    const float* __restrict__ adj, const int* __restrict__ perm,
    const int* __restrict__ inv, const float* __restrict__ gate,
    const float* __restrict__ x, unsigned* __restrict__ bm,
    float* __restrict__ x_pool)
{
    __shared__ unsigned bits[64 * 17];    // 4.25 KB
    __shared__ int sinv[NN];              // 4 KB
    if (blockIdx.x >= 512) {
        // ---- xpool role: x_pool[bi][c] = x[b][perm[bi]][c] * gate[bi]
        int id = (blockIdx.x - 512) * 1024 + threadIdx.x;  // < NB*NK*NC/4
        int c4 = id & (NC / 4 - 1);
        int bi = id >> 5;
        int b  = bi >> 9;
        int pi = perm[bi];
        float g = gate[bi];
        float4 v = *(const float4*)(x + ((size_t)b * NN + pi) * NC + c4 * 4);
        v.x *= g; v.y *= g; v.z *= g; v.w *= g;
        *(float4*)(x_pool + (size_t)id * 4) = v;
        return;
    }
    const int b = blockIdx.x >> 3;
    const int chunk = blockIdx.x & 7;    // 64 pooled rows each
    const int t = threadIdx.x;
    for (int idx = t; idx < 64 * 17; idx += 1024) bits[idx] = 0;
    for (int idx = t; idx < NN; idx += 1024) sinv[idx] = inv[b * NN + idx];
    __syncthreads();

    const float* ab = adj + (size_t)b * NN * NN;
    const int* permb = perm + b * NK + chunk * 64;
    const int g  = t >> 8;               // local row-group 0..3
    const int lt = t & 255;

    int il = g;                          // rows g, g+4, ..., g+60 (16 iters)
    float4 v0 = *(const float4*)(ab + (size_t)permb[il] * NN + lt * 4);
    float4 v1 = *(const float4*)(ab + (size_t)permb[il + 4] * NN + lt * 4);
    float4 v2 = *(const float4*)(ab + (size_t)permb[il + 8] * NN + lt * 4);
    for (int it = 0; it < 16; ++it) {
        float4 vn = v0;
        if (it < 13)                     // 3-deep prefetch
            vn = *(const float4*)(ab + (size_t)permb[il + 12] * NN + lt * 4);
        #pragma unroll
        for (int u = 0; u < 4; ++u) {
            if (((const float*)&v0)[u] != 0.0f) {
                int j = sinv[lt * 4 + u];
                if (j >= 0)
                    atomicOr(&bits[il * 17 + (j >> 5)], 1u << (j & 31));
            }
        }
        v0 = v1; v1 = v2; v2 = vn; il += 4;
    }
    __syncthreads();
    // dump: bm[b*8192 + w*512 + chunk*64 + dil] = bits[dil*17 + w]
    {
        int dil = t & 63, w = t >> 6;
        if (t < 1024)
            bm[(size_t)b * 8192 + w * 512 + chunk * 64 + dil] = bits[dil * 17 + w];
    }
}

// K3: adj_pooled[b,i,j] = (fw(i,j) | trans(j,i)) + (i==j).
// 8 blocks/graph x 64 output rows, 1024 threads. Stage ONLY the slab's
// needs: 2 trans word-cols (4 KB) + 64 fw rows into padded slab (4.25 KB).
__global__ __launch_bounds__(1024) void adj_write_kernel(
    const unsigned* __restrict__ bm, float* __restrict__ out)
{
    __shared__ unsigned tcb[2 * 512];       // trans word-cols slab*2, slab*2+1
    __shared__ unsigned fws[64 * 17];       // fw slab, padded
    const int b = blockIdx.x >> 3;
    const int slab = blockIdx.x & 7;        // rows slab*64 .. +63
    const int t = threadIdx.x;
    const unsigned* bmb = bm + (size_t)b * 8192;
    {   // trans: tcb[e*512 + j] = bmb[(slab*2+e)*512 + j]
        int e = t >> 9, j = t & 511;
        tcb[t] = bmb[(slab * 2 + e) * 512 + j];
    }
    {   // fw: fws[il*17+wi] = bmb[wi*512 + slab*64 + il]
        int il = t & 63, wi = t >> 6;
        fws[il * 17 + wi] = bmb[wi * 512 + slab * 64 + il];
    }
    __syncthreads();

    float* ob = out + ((size_t)b * NK + slab * 64) * NK;
    #pragma unroll
    for (int it = 0; it < 8; ++it) {
        int lid = it * 1024 + t;            // < 8192
        int i_loc = lid >> 7;               // 0..63
        int i = slab * 64 + i_loc;
        int j4 = (lid & 127) * 4;
        unsigned fw = fws[i_loc * 17 + (j4 >> 5)];
        uint4 tq = *(const uint4*)&tcb[(i_loc >> 5) * 512 + j4];
        float4 res;
        float* rpn = (float*)&res;
        const unsigned* tp = (const unsigned*)&tq;
        #pragma unroll
        for (int e = 0; e < 4; ++e) {
            unsigned bit = ((fw >> ((j4 + e) & 31)) | (tp[e] >> (i & 31))) & 1u;
            float f = (float)bit;
            if (i == j4 + e) f += 1.0f;
            rpn[e] = f;
        }
        *(float4*)(ob + (size_t)i_loc * NK + j4) = res;
    }
}

extern "C" void kernel_launch(void* const* d_in, const int* in_sizes, int n_in,
                              void* d_out, int out_size, void* d_ws, size_t ws_size,
                              hipStream_t stream) {
    const float* x   = (const float*)d_in[0];
    const float* adj = (const float*)d_in[1];
    const float* w   = (const float*)d_in[2];
    float* out = (float*)d_out;

    char* p = (char*)d_ws;
    unsigned* bm   = (unsigned*)p;  p += sizeof(unsigned) * NB * 16 * NK; // 2 MB
    int*      perm = (int*)p;       p += sizeof(int) * NB * NK;           // 128 KB
    float*    gate = (float*)p;     p += sizeof(float) * NB * NK;         // 128 KB
    int*      inv  = (int*)p;                                             // 256 KB

    float* x_pool     = out;                           // NB*NK*NC
    float* adj_pooled = out + (size_t)NB * NK * NC;    // NB*NK*NK

    scorerank_kernel<<<NB * 4, 1024, 0, stream>>>(x, w, perm, gate, inv);
    scan_xpool_kernel<<<512 + NB * NK * NC / 4 / 1024, 1024, 0, stream>>>(
        adj, perm, inv, gate, x, bm, x_pool);
    adj_write_kernel<<<NB * 8, 1024, 0, stream>>>(bm, adj_pooled);
}